// Round 14
// baseline (378.557 us; speedup 1.0000x reference)
//
#include <hip/hip_runtime.h>

constexpr int Cc = 512;
constexpr int Nn = 4096;   // 64*64
constexpr int Bb = 4;
#define EPS 1e-5f

using f16x8 = __attribute__((ext_vector_type(8))) _Float16;
using f32x4 = __attribute__((ext_vector_type(4))) float;
typedef unsigned short us;
typedef unsigned long long ull;

__device__ __forceinline__ us f2h(float f) {
    union { _Float16 h; us u; } v; v.h = (_Float16)f;
    return v.u;
}
__device__ __forceinline__ void gload_lds16(const void* g, void* l) {
    __builtin_amdgcn_global_load_lds(
        (const __attribute__((address_space(1))) void*)g,
        (__attribute__((address_space(3))) void*)l, 16, 0, 0);
}

// ---- stats for BOTH tensors in one launch: per (b,c) mean & rstd (ddof=1) ----
__global__ __launch_bounds__(256) void stats2_kernel(const float* __restrict__ x0,
                                                     const float* __restrict__ x1,
                                                     float* __restrict__ mean0,
                                                     float* __restrict__ rstd0,
                                                     float* __restrict__ mean1,
                                                     float* __restrict__ rstd1) {
    int bc = blockIdx.x;
    const float* row;
    float *mean, *rstd;
    int idx;
    if (bc < Bb * Cc) { idx = bc; row = x0 + (size_t)idx * Nn; mean = mean0; rstd = rstd0; }
    else              { idx = bc - Bb * Cc; row = x1 + (size_t)idx * Nn; mean = mean1; rstd = rstd1; }
    float s = 0.f, sq = 0.f;
    for (int i = threadIdx.x * 4; i < Nn; i += 256 * 4) {
        float4 v = *reinterpret_cast<const float4*>(row + i);
        s  += v.x + v.y + v.z + v.w;
        sq += v.x*v.x + v.y*v.y + v.z*v.z + v.w*v.w;
    }
    for (int off = 32; off; off >>= 1) {
        s  += __shfl_down(s, off);
        sq += __shfl_down(sq, off);
    }
    __shared__ float ls[4], lsq[4];
    int wid = threadIdx.x >> 6;
    if ((threadIdx.x & 63) == 0) { ls[wid] = s; lsq[wid] = sq; }
    __syncthreads();
    if (threadIdx.x == 0) {
        float S  = ls[0] + ls[1] + ls[2] + ls[3];
        float SQ = lsq[0] + lsq[1] + lsq[2] + lsq[3];
        float m  = S / (float)Nn;
        float var = (SQ - S * m) / (float)(Nn - 1);
        mean[idx] = m;
        rstd[idx] = rsqrtf(var + EPS);
    }
}

// ------ pack fp32 [b][c][n] -> fp16 transposed [b][n][c], inst-norm ------
__global__ __launch_bounds__(256) void pack_T(const float* __restrict__ X,
                                              const float* __restrict__ mean,
                                              const float* __restrict__ rstd,
                                              us* __restrict__ T0) {
    int b = blockIdx.z;
    int n0 = blockIdx.x * 64, c0 = blockIdx.y * 64;
    __shared__ float tile[64][65];
    const float* Xb = X + (size_t)b * Cc * Nn;
    for (int i = threadIdx.x; i < 64 * 64; i += 256) {
        int c = i >> 6, n = i & 63;
        float v = Xb[(size_t)(c0 + c) * Nn + n0 + n];
        int cg = b * Cc + c0 + c;
        tile[c][n] = (v - mean[cg]) * rstd[cg];
    }
    __syncthreads();
    us* Pb = T0 + (size_t)b * Nn * Cc;
    for (int i = threadIdx.x; i < 64 * 64; i += 256) {
        int n = i >> 6, c = i & 63;
        Pb[(size_t)(n0 + n) * Cc + c0 + c] = f2h(tile[c][n]);
    }
}

// ------ style: ONE read -> normed SN and raw SR, both fp16 [b][n][c] ------
__global__ __launch_bounds__(256) void pack_style(const float* __restrict__ X,
                                                  const float* __restrict__ mean,
                                                  const float* __restrict__ rstd,
                                                  us* __restrict__ SNo,
                                                  us* __restrict__ SRo) {
    int b = blockIdx.z;
    int n0 = blockIdx.x * 64, c0 = blockIdx.y * 64;
    __shared__ float tile[64][65];
    const float* Xb = X + (size_t)b * Cc * Nn;
    for (int i = threadIdx.x; i < 64 * 64; i += 256) {
        int c = i >> 6, n = i & 63;
        tile[c][n] = Xb[(size_t)(c0 + c) * Nn + n0 + n];   // raw
    }
    __syncthreads();
    us* Nb = SNo + (size_t)b * Nn * Cc;
    us* Rb = SRo + (size_t)b * Nn * Cc;
    for (int i = threadIdx.x; i < 64 * 64; i += 256) {
        int n = i >> 6, c = i & 63;
        float raw = tile[c][n];
        int cg = b * Cc + c0 + c;
        size_t off = (size_t)(n0 + n) * Cc + c0 + c;
        Rb[off] = f2h(raw);
        Nb[off] = f2h((raw - mean[cg]) * rstd[cg]);
    }
}

// ------ pack the four 512x512 weights to fp16 ------
__global__ __launch_bounds__(256) void pack_w(const float* __restrict__ fw, const float* __restrict__ gw,
                                              const float* __restrict__ hw, const float* __restrict__ ow,
                                              us* __restrict__ fo, us* __restrict__ go,
                                              us* __restrict__ ho, us* __restrict__ oo) {
    int i = blockIdx.x * 256 + threadIdx.x;
    if (i >= Cc * Cc) return;
    fo[i] = f2h(fw[i]);
    go[i] = f2h(gw[i]);
    ho[i] = f2h(hw[i]);
    oo[i] = f2h(ow[i]);
}

// ------------- fp16 MFMA GEMM: C[m][n'] = sum_k A[m][k]*B[n'][k] -------------
// A m-major (lda), B n'-major (ldb). BMxBN tile, BK per barrier pair
// (BK/32 sub-tiles [rows][32]), 4 waves (2x2), frags mfma_f32_16x16x32_f16.
// EPI: 0 fp32 store, 1 fp16 store.  BIAS: 0 none, 1 bias[row], 2 bias[col].
// SWZ: 0 none; 1 chunked XCD swizzle (nwg % 8 == 0);
//      2 region XCD swizzle (4x2 rectangles; gridDim.y%4==0, gridDim.x%2==0).
// blockIdx.z = batch slab via strideA/strideB/strideC.
// Epilogue: LDS-staged, vectorized float4 / packed-8B stores.
template <int EPI, int BIAS, bool RESID, int BM, int BN, int BK, int SWZ>
__global__ __launch_bounds__(256) void mfma_gemm(
    const us* __restrict__ A, int lda, long long strideA,
    const us* __restrict__ B, int ldb, long long strideB,
    void* __restrict__ out0, int ldc, long long strideC,
    const float* __restrict__ bias, const float* __restrict__ resid, long long strideR,
    int K) {
    constexpr int WM = BM / 2, WN = BN / 2;
    constexpr int MI = WM / 16, NI = WN / 16;
    constexpr int AE = BM * BK, BE = BN * BK;
    constexpr int ACH = AE / 512, BCH = BE / 512;
    __shared__ __attribute__((aligned(16))) us smem[AE + BE];
    us* As = smem;
    us* Bs = smem + AE;

    int bz = blockIdx.z;
    const us* Ab = A + (size_t)bz * strideA;
    const us* Bbp = B + (size_t)bz * strideB;

    int bx = blockIdx.x, by = blockIdx.y;
    if constexpr (SWZ == 1) {
        int nwg = gridDim.x * gridDim.y;          // must be % 8 == 0
        int bid = blockIdx.x + gridDim.x * blockIdx.y;
        int cpx = nwg >> 3;
        int swz = (bid & 7) * cpx + (bid >> 3);
        bx = swz % gridDim.x;
        by = swz / gridDim.x;
    } else if constexpr (SWZ == 2) {
        int bid = blockIdx.x + gridDim.x * blockIdx.y;
        int xcd = bid & 7;
        int idx = bid >> 3;
        int rpr = gridDim.y >> 2;
        int cpr = gridDim.x >> 1;
        int row0 = (xcd >> 1) * rpr;
        int col0 = (xcd & 1) * cpr;
        by = row0 + idx / cpr;
        bx = col0 + idx % cpr;
    }
    int m0 = by * BM, n0 = bx * BN;
    int tid = threadIdx.x, wave = tid >> 6, lane = tid & 63;
    int wr = wave >> 1, wc = wave & 1;
    int lr = lane & 15, lg = lane >> 4;

    f32x4 acc[MI][NI];
#pragma unroll
    for (int i = 0; i < MI; ++i)
#pragma unroll
        for (int j = 0; j < NI; ++j) acc[i][j] = (f32x4){0.f, 0.f, 0.f, 0.f};

    for (int k0 = 0; k0 < K; k0 += BK) {
        __syncthreads();
#pragma unroll
        for (int ch = wave; ch < ACH; ch += 4) {
            int e0 = ch * 512 + lane * 8;
            int kb = e0 / (BM * 32);
            int rem = e0 - kb * (BM * 32);
            int rr = rem >> 5, cc = rem & 31;
            gload_lds16(Ab + (size_t)(m0 + rr) * lda + k0 + kb * 32 + cc, As + ch * 512);
        }
#pragma unroll
        for (int ch = wave; ch < BCH; ch += 4) {
            int e0 = ch * 512 + lane * 8;
            int kb = e0 / (BN * 32);
            int rem = e0 - kb * (BN * 32);
            int rr = rem >> 5, cc = rem & 31;
            gload_lds16(Bbp + (size_t)(n0 + rr) * ldb + k0 + kb * 32 + cc, Bs + ch * 512);
        }
        asm volatile("s_waitcnt vmcnt(0)" ::: "memory");
        __syncthreads();

#pragma unroll
        for (int kb = 0; kb < BK / 32; ++kb) {
            const us* Abase = As + kb * BM * 32;
            const us* Bbase = Bs + kb * BN * 32;
            f16x8 a[MI], b[NI];
#pragma unroll
            for (int x = 0; x < MI; ++x)
                a[x] = *reinterpret_cast<const f16x8*>(&Abase[(wr * WM + x * 16 + lr) * 32 + lg * 8]);
#pragma unroll
            for (int x = 0; x < NI; ++x)
                b[x] = *reinterpret_cast<const f16x8*>(&Bbase[(wc * WN + x * 16 + lr) * 32 + lg * 8]);
#pragma unroll
            for (int mi = 0; mi < MI; ++mi)
#pragma unroll
                for (int ni = 0; ni < NI; ++ni)
                    acc[mi][ni] = __builtin_amdgcn_mfma_f32_16x16x32_f16(a[mi], b[ni], acc[mi][ni], 0, 0, 0);
        }
    }

    // -------- LDS-staged epilogue: per mi, stage 32 rows x BN, store wide --------
    constexpr int SP = BN + 4;                 // padded f32 stride
    float* sst = reinterpret_cast<float*>(smem);
    constexpr int CSEG = BN / 8;               // cols per thread (8 thr/row, 32 rows)
    int rl = tid >> 3;                         // 0..31 staged-row
    int cb = (tid & 7) * CSEG;                 // col base for readback
#pragma unroll
    for (int mi = 0; mi < MI; ++mi) {
        __syncthreads();
#pragma unroll
        for (int ni = 0; ni < NI; ++ni) {
#pragma unroll
            for (int r = 0; r < 4; ++r)
                sst[(wr * 16 + lg * 4 + r) * SP + wc * WN + ni * 16 + lr] = acc[mi][ni][r];
        }
        __syncthreads();
        int grow = m0 + (rl >> 4) * WM + mi * 16 + (rl & 15);
        float bs = 0.f;
        if constexpr (BIAS == 1) bs = bias[grow];
#pragma unroll
        for (int j = 0; j < CSEG / 4; ++j) {
            int col = n0 + cb + j * 4;
            float4 v = *reinterpret_cast<const float4*>(&sst[rl * SP + cb + j * 4]);
            if constexpr (BIAS == 1) { v.x += bs; v.y += bs; v.z += bs; v.w += bs; }
            if constexpr (BIAS == 2) {
                const float4 bv = *reinterpret_cast<const float4*>(&bias[col]);
                v.x += bv.x; v.y += bv.y; v.z += bv.z; v.w += bv.w;
            }
            size_t off = (size_t)bz * strideC + (size_t)grow * ldc + col;
            if constexpr (RESID) {
                const float4 rr4 = *reinterpret_cast<const float4*>(
                    &resid[(size_t)bz * strideR + (size_t)grow * ldc + col]);
                v.x += rr4.x; v.y += rr4.y; v.z += rr4.z; v.w += rr4.w;
            }
            if constexpr (EPI == 0) {
                *reinterpret_cast<float4*>(&((float*)out0)[off]) = v;
            } else {
                ull pk = (ull)f2h(v.x) | ((ull)f2h(v.y) << 16)
                       | ((ull)f2h(v.z) << 32) | ((ull)f2h(v.w) << 48);
                *reinterpret_cast<ull*>(&((us*)out0)[off]) = pk;
            }
        }
    }
}

// ------- row softmax fp16 IN-PLACE (S row -> normalized P row) -------
// grid (Nn, nslab): blockIdx.y selects a 32MB S slab.
__global__ __launch_bounds__(256) void softmax_kernel(us* __restrict__ S) {
    us* rowp = S + (size_t)blockIdx.y * ((size_t)Nn * Nn) + (size_t)blockIdx.x * Nn;
    f16x8* r8 = reinterpret_cast<f16x8*>(rowp);
    int t = threadIdx.x;
    float f[16];
    float mx = -1e30f;
#pragma unroll
    for (int j = 0; j < 2; ++j) {
        f16x8 v = r8[t + 256 * j];
#pragma unroll
        for (int e = 0; e < 8; ++e) {
            f[j * 8 + e] = (float)v[e];
            mx = fmaxf(mx, f[j * 8 + e]);
        }
    }
    for (int off = 32; off; off >>= 1) mx = fmaxf(mx, __shfl_down(mx, off));
    __shared__ float redm[4], reds[4];
    int wid = t >> 6;
    if ((t & 63) == 0) redm[wid] = mx;
    __syncthreads();
    mx = fmaxf(fmaxf(redm[0], redm[1]), fmaxf(redm[2], redm[3]));
    float s = 0.f;
#pragma unroll
    for (int j = 0; j < 16; ++j) {
        f[j] = __expf(f[j] - mx);
        s += f[j];
    }
    for (int off = 32; off; off >>= 1) s += __shfl_down(s, off);
    if ((t & 63) == 0) reds[wid] = s;
    __syncthreads();
    s = reds[0] + reds[1] + reds[2] + reds[3];
    float inv = 1.f / s;
#pragma unroll
    for (int j = 0; j < 2; ++j) {
        f16x8 o;
#pragma unroll
        for (int e = 0; e < 8; ++e) o[e] = (_Float16)(f[j * 8 + e] * inv);
        r8[t + 256 * j] = o;
    }
}

extern "C" void kernel_launch(void* const* d_in, const int* in_sizes, int n_in,
                              void* d_out, int out_size, void* d_ws, size_t ws_size,
                              hipStream_t stream) {
    const float* content = (const float*)d_in[0];
    const float* style   = (const float*)d_in[1];
    const float* f_w = (const float*)d_in[2];
    const float* f_b = (const float*)d_in[3];
    const float* g_w = (const float*)d_in[4];
    const float* g_b = (const float*)d_in[5];
    const float* h_w = (const float*)d_in[6];
    const float* h_b = (const float*)d_in[7];
    const float* o_w = (const float*)d_in[8];
    const float* o_b = (const float*)d_in[9];
    float* out = (float*)d_out;
    char* ws = (char*)d_ws;

    const size_t PB   = (size_t)Cc * Nn;       // 2,097,152 elems per batch-plane
    const size_t TEN  = PB * Bb;               // 8,388,608 elems (16 MB as fp16)
    const size_t SMAT = (size_t)Nn * Nn;       // 16,777,216 elems (32 MB as fp16)

    // [0,48MB): packed inputs fp16: CN, SN, SR.
    us* CN = (us*)ws;
    us* SN = CN + TEN;
    us* SR = SN + TEN;
    // [48,112MB): conv outputs fp16
    us* FT  = SR + TEN;                        // F^T [q][c]
    us* GT  = FT + TEN;                        // G^T [s][c]
    us* Hbf = GT + TEN;                        // H   [c'][s]
    us* OT  = Hbf + TEN;                       // O^T [q][c']
    // [112MB,...): weights fp16, stats, then pair S/P fp16 (2 x 32MB)
    us* fwh = OT + TEN;
    us* gwh = fwh + Cc * Cc;
    us* hwb = gwh + Cc * Cc;
    us* owb = hwb + Cc * Cc;
    float* meanC = (float*)(owb + Cc * Cc);
    float* rstdC = meanC + Bb * Cc;
    float* meanS = rstdC + Bb * Cc;
    float* rstdS = meanS + Bb * Cc;
    us* S2 = (us*)(rstdS + Bb * Cc);           // 2 slabs: S/P for a batch PAIR
                                               // peak ws use ≈ 178 MB (proven ≤ r5's 214)

    stats2_kernel<<<2 * Bb * Cc, 256, 0, stream>>>(content, style,
                                                   meanC, rstdC, meanS, rstdS);

    dim3 pgrid(Nn / 64, Cc / 64, Bb);
    pack_T<<<pgrid, 256, 0, stream>>>(content, meanC, rstdC, CN);
    pack_style<<<pgrid, 256, 0, stream>>>(style, meanS, rstdS, SN, SR);
    pack_w<<<(Cc * Cc + 255) / 256, 256, 0, stream>>>(f_w, g_w, h_w, o_w,
                                                      fwh, gwh, hwb, owb);

    // F^T[q][c'] = sum_c CN[q][c] f_w[c'][c] + f_b[c']  (M=4096,N=512,K=512)
    mfma_gemm<1, 2, false, 64, 64, 64, 1><<<dim3(Cc / 64, Nn / 64, Bb), 256, 0, stream>>>(
        CN, Cc, (long long)PB, fwh, Cc, 0,
        FT, Cc, (long long)PB, f_b, nullptr, 0, Cc);
    // G^T likewise
    mfma_gemm<1, 2, false, 64, 64, 64, 1><<<dim3(Cc / 64, Nn / 64, Bb), 256, 0, stream>>>(
        SN, Cc, (long long)PB, gwh, Cc, 0,
        GT, Cc, (long long)PB, g_b, nullptr, 0, Cc);
    // H[c'][s] = sum_c h_w[c'][c] SR[s][c] + h_b[c']   (M=512,N=4096,K=512)
    mfma_gemm<1, 1, false, 64, 64, 64, 1><<<dim3(Nn / 64, Cc / 64, Bb), 256, 0, stream>>>(
        hwb, Cc, 0, SR, Cc, (long long)PB,
        Hbf, Nn, (long long)PB, h_b, nullptr, 0, Cc);

    // attention in batch PAIRS: S (z=2) -> in-place softmax (z=2) -> PV (z=2).
    for (int pair = 0; pair < Bb / 2; ++pair) {
        const size_t tb = (size_t)(pair * 2) * PB;
        // S[q][s] = sum_c F^T[q][c] G^T[s][c]  (M=N=4096,K=512), fp16 out
        mfma_gemm<1, 0, false, 128, 128, 64, 2><<<dim3(32, 32, 2), 256, 0, stream>>>(
            FT + tb, Cc, (long long)PB, GT + tb, Cc, (long long)PB,
            S2, Nn, (long long)SMAT, nullptr, nullptr, 0, Cc);
        softmax_kernel<<<dim3(Nn, 2), 256, 0, stream>>>(S2);
        // O^T[q][c'] = sum_s P[q][s] H[c'][s]  (M=4096,N=512,K=4096), fp16 out
        // 128x64 tile: 8 MFMA per 6 ds_read per wave-kstep (vs 4:4 at 64x64)
        mfma_gemm<1, 0, false, 128, 64, 64, 1><<<dim3(Cc / 64, Nn / 128, 2), 256, 0, stream>>>(
            S2, Nn, (long long)SMAT, Hbf + tb, Nn, (long long)PB,
            OT + tb, Cc, (long long)PB, nullptr, nullptr, 0, Nn);
    }

    // out[c'][n] = sum_c o_w[c'][c] O^T[n][c] + o_b[c'] + content[c'][n]
    mfma_gemm<0, 1, true, 64, 64, 64, 1><<<dim3(Nn / 64, Cc / 64, Bb), 256, 0, stream>>>(
        owb, Cc, 0, OT, Cc, (long long)PB,
        out, Nn, (long long)PB, o_b, content, (long long)PB, Cc);
}

// Round 15
// 364.164 us; speedup vs baseline: 1.0395x; 1.0395x over previous
//
#include <hip/hip_runtime.h>

constexpr int Cc = 512;
constexpr int Nn = 4096;   // 64*64
constexpr int Bb = 4;
#define EPS 1e-5f

using f16x8 = __attribute__((ext_vector_type(8))) _Float16;
using f32x4 = __attribute__((ext_vector_type(4))) float;
typedef unsigned short us;
typedef unsigned long long ull;

__device__ __forceinline__ us f2h(float f) {
    union { _Float16 h; us u; } v; v.h = (_Float16)f;
    return v.u;
}
__device__ __forceinline__ void gload_lds16(const void* g, void* l) {
    __builtin_amdgcn_global_load_lds(
        (const __attribute__((address_space(1))) void*)g,
        (__attribute__((address_space(3))) void*)l, 16, 0, 0);
}

// ---- stats for BOTH tensors in one launch: per (b,c) mean & rstd (ddof=1) ----
__global__ __launch_bounds__(256) void stats2_kernel(const float* __restrict__ x0,
                                                     const float* __restrict__ x1,
                                                     float* __restrict__ mean0,
                                                     float* __restrict__ rstd0,
                                                     float* __restrict__ mean1,
                                                     float* __restrict__ rstd1) {
    int bc = blockIdx.x;
    const float* row;
    float *mean, *rstd;
    int idx;
    if (bc < Bb * Cc) { idx = bc; row = x0 + (size_t)idx * Nn; mean = mean0; rstd = rstd0; }
    else              { idx = bc - Bb * Cc; row = x1 + (size_t)idx * Nn; mean = mean1; rstd = rstd1; }
    float s = 0.f, sq = 0.f;
    for (int i = threadIdx.x * 4; i < Nn; i += 256 * 4) {
        float4 v = *reinterpret_cast<const float4*>(row + i);
        s  += v.x + v.y + v.z + v.w;
        sq += v.x*v.x + v.y*v.y + v.z*v.z + v.w*v.w;
    }
    for (int off = 32; off; off >>= 1) {
        s  += __shfl_down(s, off);
        sq += __shfl_down(sq, off);
    }
    __shared__ float ls[4], lsq[4];
    int wid = threadIdx.x >> 6;
    if ((threadIdx.x & 63) == 0) { ls[wid] = s; lsq[wid] = sq; }
    __syncthreads();
    if (threadIdx.x == 0) {
        float S  = ls[0] + ls[1] + ls[2] + ls[3];
        float SQ = lsq[0] + lsq[1] + lsq[2] + lsq[3];
        float m  = S / (float)Nn;
        float var = (SQ - S * m) / (float)(Nn - 1);
        mean[idx] = m;
        rstd[idx] = rsqrtf(var + EPS);
    }
}

// ------ pack fp32 [b][c][n] -> fp16 transposed [b][n][c], inst-norm ------
__global__ __launch_bounds__(256) void pack_T(const float* __restrict__ X,
                                              const float* __restrict__ mean,
                                              const float* __restrict__ rstd,
                                              us* __restrict__ T0) {
    int b = blockIdx.z;
    int n0 = blockIdx.x * 64, c0 = blockIdx.y * 64;
    __shared__ float tile[64][65];
    const float* Xb = X + (size_t)b * Cc * Nn;
    for (int i = threadIdx.x; i < 64 * 64; i += 256) {
        int c = i >> 6, n = i & 63;
        float v = Xb[(size_t)(c0 + c) * Nn + n0 + n];
        int cg = b * Cc + c0 + c;
        tile[c][n] = (v - mean[cg]) * rstd[cg];
    }
    __syncthreads();
    us* Pb = T0 + (size_t)b * Nn * Cc;
    for (int i = threadIdx.x; i < 64 * 64; i += 256) {
        int n = i >> 6, c = i & 63;
        Pb[(size_t)(n0 + n) * Cc + c0 + c] = f2h(tile[c][n]);
    }
}

// ------ style: ONE read -> normed SN and raw SR, both fp16 [b][n][c] ------
__global__ __launch_bounds__(256) void pack_style(const float* __restrict__ X,
                                                  const float* __restrict__ mean,
                                                  const float* __restrict__ rstd,
                                                  us* __restrict__ SNo,
                                                  us* __restrict__ SRo) {
    int b = blockIdx.z;
    int n0 = blockIdx.x * 64, c0 = blockIdx.y * 64;
    __shared__ float tile[64][65];
    const float* Xb = X + (size_t)b * Cc * Nn;
    for (int i = threadIdx.x; i < 64 * 64; i += 256) {
        int c = i >> 6, n = i & 63;
        tile[c][n] = Xb[(size_t)(c0 + c) * Nn + n0 + n];   // raw
    }
    __syncthreads();
    us* Nb = SNo + (size_t)b * Nn * Cc;
    us* Rb = SRo + (size_t)b * Nn * Cc;
    for (int i = threadIdx.x; i < 64 * 64; i += 256) {
        int n = i >> 6, c = i & 63;
        float raw = tile[c][n];
        int cg = b * Cc + c0 + c;
        size_t off = (size_t)(n0 + n) * Cc + c0 + c;
        Rb[off] = f2h(raw);
        Nb[off] = f2h((raw - mean[cg]) * rstd[cg]);
    }
}

// ------ pack the four 512x512 weights to fp16 ------
__global__ __launch_bounds__(256) void pack_w(const float* __restrict__ fw, const float* __restrict__ gw,
                                              const float* __restrict__ hw, const float* __restrict__ ow,
                                              us* __restrict__ fo, us* __restrict__ go,
                                              us* __restrict__ ho, us* __restrict__ oo) {
    int i = blockIdx.x * 256 + threadIdx.x;
    if (i >= Cc * Cc) return;
    fo[i] = f2h(fw[i]);
    go[i] = f2h(gw[i]);
    ho[i] = f2h(hw[i]);
    oo[i] = f2h(ow[i]);
}

// ------------- fp16 MFMA GEMM: C[m][n'] = sum_k A[m][k]*B[n'][k] -------------
// A m-major (lda), B n'-major (ldb). BMxBN tile, BK per barrier pair
// (BK/32 sub-tiles [rows][32]), 4 waves (2x2), frags mfma_f32_16x16x32_f16.
// EPI: 0 fp32 store, 1 fp16 store.  BIAS: 0 none, 1 bias[row], 2 bias[col].
// SWZ: 0 none; 1 chunked XCD swizzle (nwg % 8 == 0);
//      2 region XCD swizzle (4x2 rectangles; gridDim.y%4==0, gridDim.x%2==0).
// blockIdx.z = batch slab via strideA/strideB/strideC.
// Epilogue: LDS-staged, vectorized float4 / packed-8B stores.
template <int EPI, int BIAS, bool RESID, int BM, int BN, int BK, int SWZ>
__global__ __launch_bounds__(256) void mfma_gemm(
    const us* __restrict__ A, int lda, long long strideA,
    const us* __restrict__ B, int ldb, long long strideB,
    void* __restrict__ out0, int ldc, long long strideC,
    const float* __restrict__ bias, const float* __restrict__ resid, long long strideR,
    int K) {
    constexpr int WM = BM / 2, WN = BN / 2;
    constexpr int MI = WM / 16, NI = WN / 16;
    constexpr int AE = BM * BK, BE = BN * BK;
    constexpr int ACH = AE / 512, BCH = BE / 512;
    __shared__ __attribute__((aligned(16))) us smem[AE + BE];
    us* As = smem;
    us* Bs = smem + AE;

    int bz = blockIdx.z;
    const us* Ab = A + (size_t)bz * strideA;
    const us* Bbp = B + (size_t)bz * strideB;

    int bx = blockIdx.x, by = blockIdx.y;
    if constexpr (SWZ == 1) {
        int nwg = gridDim.x * gridDim.y;          // must be % 8 == 0
        int bid = blockIdx.x + gridDim.x * blockIdx.y;
        int cpx = nwg >> 3;
        int swz = (bid & 7) * cpx + (bid >> 3);
        bx = swz % gridDim.x;
        by = swz / gridDim.x;
    } else if constexpr (SWZ == 2) {
        int bid = blockIdx.x + gridDim.x * blockIdx.y;
        int xcd = bid & 7;
        int idx = bid >> 3;
        int rpr = gridDim.y >> 2;
        int cpr = gridDim.x >> 1;
        int row0 = (xcd >> 1) * rpr;
        int col0 = (xcd & 1) * cpr;
        by = row0 + idx / cpr;
        bx = col0 + idx % cpr;
    }
    int m0 = by * BM, n0 = bx * BN;
    int tid = threadIdx.x, wave = tid >> 6, lane = tid & 63;
    int wr = wave >> 1, wc = wave & 1;
    int lr = lane & 15, lg = lane >> 4;

    f32x4 acc[MI][NI];
#pragma unroll
    for (int i = 0; i < MI; ++i)
#pragma unroll
        for (int j = 0; j < NI; ++j) acc[i][j] = (f32x4){0.f, 0.f, 0.f, 0.f};

    for (int k0 = 0; k0 < K; k0 += BK) {
        __syncthreads();
#pragma unroll
        for (int ch = wave; ch < ACH; ch += 4) {
            int e0 = ch * 512 + lane * 8;
            int kb = e0 / (BM * 32);
            int rem = e0 - kb * (BM * 32);
            int rr = rem >> 5, cc = rem & 31;
            gload_lds16(Ab + (size_t)(m0 + rr) * lda + k0 + kb * 32 + cc, As + ch * 512);
        }
#pragma unroll
        for (int ch = wave; ch < BCH; ch += 4) {
            int e0 = ch * 512 + lane * 8;
            int kb = e0 / (BN * 32);
            int rem = e0 - kb * (BN * 32);
            int rr = rem >> 5, cc = rem & 31;
            gload_lds16(Bbp + (size_t)(n0 + rr) * ldb + k0 + kb * 32 + cc, Bs + ch * 512);
        }
        asm volatile("s_waitcnt vmcnt(0)" ::: "memory");
        __syncthreads();

#pragma unroll
        for (int kb = 0; kb < BK / 32; ++kb) {
            const us* Abase = As + kb * BM * 32;
            const us* Bbase = Bs + kb * BN * 32;
            f16x8 a[MI], b[NI];
#pragma unroll
            for (int x = 0; x < MI; ++x)
                a[x] = *reinterpret_cast<const f16x8*>(&Abase[(wr * WM + x * 16 + lr) * 32 + lg * 8]);
#pragma unroll
            for (int x = 0; x < NI; ++x)
                b[x] = *reinterpret_cast<const f16x8*>(&Bbase[(wc * WN + x * 16 + lr) * 32 + lg * 8]);
#pragma unroll
            for (int mi = 0; mi < MI; ++mi)
#pragma unroll
                for (int ni = 0; ni < NI; ++ni)
                    acc[mi][ni] = __builtin_amdgcn_mfma_f32_16x16x32_f16(a[mi], b[ni], acc[mi][ni], 0, 0, 0);
        }
    }

    // -------- LDS-staged epilogue: per mi, stage 32 rows x BN, store wide --------
    constexpr int SP = BN + 4;                 // padded f32 stride
    float* sst = reinterpret_cast<float*>(smem);
    constexpr int CSEG = BN / 8;               // cols per thread (8 thr/row, 32 rows)
    int rl = tid >> 3;                         // 0..31 staged-row
    int cb = (tid & 7) * CSEG;                 // col base for readback
#pragma unroll
    for (int mi = 0; mi < MI; ++mi) {
        __syncthreads();
#pragma unroll
        for (int ni = 0; ni < NI; ++ni) {
#pragma unroll
            for (int r = 0; r < 4; ++r)
                sst[(wr * 16 + lg * 4 + r) * SP + wc * WN + ni * 16 + lr] = acc[mi][ni][r];
        }
        __syncthreads();
        int grow = m0 + (rl >> 4) * WM + mi * 16 + (rl & 15);
        float bs = 0.f;
        if constexpr (BIAS == 1) bs = bias[grow];
#pragma unroll
        for (int j = 0; j < CSEG / 4; ++j) {
            int col = n0 + cb + j * 4;
            float4 v = *reinterpret_cast<const float4*>(&sst[rl * SP + cb + j * 4]);
            if constexpr (BIAS == 1) { v.x += bs; v.y += bs; v.z += bs; v.w += bs; }
            if constexpr (BIAS == 2) {
                const float4 bv = *reinterpret_cast<const float4*>(&bias[col]);
                v.x += bv.x; v.y += bv.y; v.z += bv.z; v.w += bv.w;
            }
            size_t off = (size_t)bz * strideC + (size_t)grow * ldc + col;
            if constexpr (RESID) {
                const float4 rr4 = *reinterpret_cast<const float4*>(
                    &resid[(size_t)bz * strideR + (size_t)grow * ldc + col]);
                v.x += rr4.x; v.y += rr4.y; v.z += rr4.z; v.w += rr4.w;
            }
            if constexpr (EPI == 0) {
                *reinterpret_cast<float4*>(&((float*)out0)[off]) = v;
            } else {
                ull pk = (ull)f2h(v.x) | ((ull)f2h(v.y) << 16)
                       | ((ull)f2h(v.z) << 32) | ((ull)f2h(v.w) << 48);
                *reinterpret_cast<ull*>(&((us*)out0)[off]) = pk;
            }
        }
    }
}

// ------- row softmax fp16 IN-PLACE (S row -> normalized P row) -------
// grid (Nn, nslab): blockIdx.y selects a 32MB S slab.
__global__ __launch_bounds__(256) void softmax_kernel(us* __restrict__ S) {
    us* rowp = S + (size_t)blockIdx.y * ((size_t)Nn * Nn) + (size_t)blockIdx.x * Nn;
    f16x8* r8 = reinterpret_cast<f16x8*>(rowp);
    int t = threadIdx.x;
    float f[16];
    float mx = -1e30f;
#pragma unroll
    for (int j = 0; j < 2; ++j) {
        f16x8 v = r8[t + 256 * j];
#pragma unroll
        for (int e = 0; e < 8; ++e) {
            f[j * 8 + e] = (float)v[e];
            mx = fmaxf(mx, f[j * 8 + e]);
        }
    }
    for (int off = 32; off; off >>= 1) mx = fmaxf(mx, __shfl_down(mx, off));
    __shared__ float redm[4], reds[4];
    int wid = t >> 6;
    if ((t & 63) == 0) redm[wid] = mx;
    __syncthreads();
    mx = fmaxf(fmaxf(redm[0], redm[1]), fmaxf(redm[2], redm[3]));
    float s = 0.f;
#pragma unroll
    for (int j = 0; j < 16; ++j) {
        f[j] = __expf(f[j] - mx);
        s += f[j];
    }
    for (int off = 32; off; off >>= 1) s += __shfl_down(s, off);
    if ((t & 63) == 0) reds[wid] = s;
    __syncthreads();
    s = reds[0] + reds[1] + reds[2] + reds[3];
    float inv = 1.f / s;
#pragma unroll
    for (int j = 0; j < 2; ++j) {
        f16x8 o;
#pragma unroll
        for (int e = 0; e < 8; ++e) o[e] = (_Float16)(f[j * 8 + e] * inv);
        r8[t + 256 * j] = o;
    }
}

extern "C" void kernel_launch(void* const* d_in, const int* in_sizes, int n_in,
                              void* d_out, int out_size, void* d_ws, size_t ws_size,
                              hipStream_t stream) {
    const float* content = (const float*)d_in[0];
    const float* style   = (const float*)d_in[1];
    const float* f_w = (const float*)d_in[2];
    const float* f_b = (const float*)d_in[3];
    const float* g_w = (const float*)d_in[4];
    const float* g_b = (const float*)d_in[5];
    const float* h_w = (const float*)d_in[6];
    const float* h_b = (const float*)d_in[7];
    const float* o_w = (const float*)d_in[8];
    const float* o_b = (const float*)d_in[9];
    float* out = (float*)d_out;
    char* ws = (char*)d_ws;

    const size_t PB   = (size_t)Cc * Nn;       // 2,097,152 elems per batch-plane
    const size_t TEN  = PB * Bb;               // 8,388,608 elems (16 MB as fp16)
    const size_t SMAT = (size_t)Nn * Nn;       // 16,777,216 elems (32 MB as fp16)

    // Workspace layout (peak ~194 MB, proven <= r5's 214 MB):
    // [0,64MB): conv outputs fp16 (FT, GT, Hbf, OT)
    us* FT  = (us*)ws;                         // F^T [q][c]
    us* GT  = FT + TEN;                        // G^T [s][c]
    us* Hbf = GT + TEN;                        // H   [c'][s]
    us* OT  = Hbf + TEN;                       // O^T [q][c']
    // [64,66MB): weights fp16 + stats
    us* fwh = OT + TEN;
    us* gwh = fwh + Cc * Cc;
    us* hwb = gwh + Cc * Cc;
    us* owb = hwb + Cc * Cc;
    float* meanC = (float*)(owb + Cc * Cc);
    float* rstdC = meanC + Bb * Cc;
    float* meanS = rstdC + Bb * Cc;
    float* rstdS = meanS + Bb * Cc;
    // [66,114MB): packed inputs fp16 (CN, SN, SR) — dead before attention.
    us* CN = (us*)(rstdS + Bb * Cc);
    us* SN = CN + TEN;
    us* SR = SN + TEN;
    // [66,194MB): S/P fp16, ALL FOUR batches — overlays dead CN/SN/SR.
    us* S4 = CN;

    stats2_kernel<<<2 * Bb * Cc, 256, 0, stream>>>(content, style,
                                                   meanC, rstdC, meanS, rstdS);

    dim3 pgrid(Nn / 64, Cc / 64, Bb);
    pack_T<<<pgrid, 256, 0, stream>>>(content, meanC, rstdC, CN);
    pack_style<<<pgrid, 256, 0, stream>>>(style, meanS, rstdS, SN, SR);
    pack_w<<<(Cc * Cc + 255) / 256, 256, 0, stream>>>(f_w, g_w, h_w, o_w,
                                                      fwh, gwh, hwb, owb);

    // F^T[q][c'] = sum_c CN[q][c] f_w[c'][c] + f_b[c']  (M=4096,N=512,K=512)
    mfma_gemm<1, 2, false, 64, 64, 64, 1><<<dim3(Cc / 64, Nn / 64, Bb), 256, 0, stream>>>(
        CN, Cc, (long long)PB, fwh, Cc, 0,
        FT, Cc, (long long)PB, f_b, nullptr, 0, Cc);
    // G^T likewise
    mfma_gemm<1, 2, false, 64, 64, 64, 1><<<dim3(Cc / 64, Nn / 64, Bb), 256, 0, stream>>>(
        SN, Cc, (long long)PB, gwh, Cc, 0,
        GT, Cc, (long long)PB, g_b, nullptr, 0, Cc);
    // H[c'][s] = sum_c h_w[c'][c] SR[s][c] + h_b[c']   (M=512,N=4096,K=512)
    mfma_gemm<1, 1, false, 64, 64, 64, 1><<<dim3(Nn / 64, Cc / 64, Bb), 256, 0, stream>>>(
        hwb, Cc, 0, SR, Cc, (long long)PB,
        Hbf, Nn, (long long)PB, h_b, nullptr, 0, Cc);
    // (CN/SN/SR are now dead; S4 overlays them.)

    // S[q][s] = sum_c F^T[q][c] G^T[s][c]  (M=N=4096,K=512), fp16 out, all batches
    mfma_gemm<1, 0, false, 128, 128, 64, 2><<<dim3(32, 32, Bb), 256, 0, stream>>>(
        FT, Cc, (long long)PB, GT, Cc, (long long)PB,
        S4, Nn, (long long)SMAT, nullptr, nullptr, 0, Cc);
    softmax_kernel<<<dim3(Nn, Bb), 256, 0, stream>>>(S4);
    // O^T[q][c'] = sum_s P[q][s] H[c'][s]  (M=4096,N=512,K=4096), fp16 out
    // all batches: 2048 blocks = 8 blocks/CU (occupancy, the r13 PV limiter)
    mfma_gemm<1, 0, false, 64, 64, 64, 1><<<dim3(Cc / 64, Nn / 64, Bb), 256, 0, stream>>>(
        S4, Nn, (long long)SMAT, Hbf, Nn, (long long)PB,
        OT, Cc, (long long)PB, nullptr, nullptr, 0, Nn);

    // out[c'][n] = sum_c o_w[c'][c] O^T[n][c] + o_b[c'] + content[c'][n]
    mfma_gemm<0, 1, true, 64, 64, 64, 1><<<dim3(Nn / 64, Cc / 64, Bb), 256, 0, stream>>>(
        owb, Cc, 0, OT, Cc, (long long)PB,
        out, Nn, (long long)PB, o_b, content, (long long)PB, Cc);
}

// Round 16
// 358.815 us; speedup vs baseline: 1.0550x; 1.0149x over previous
//
#include <hip/hip_runtime.h>

constexpr int Cc = 512;
constexpr int Nn = 4096;   // 64*64
constexpr int Bb = 4;
#define EPS 1e-5f

using f16x8 = __attribute__((ext_vector_type(8))) _Float16;
using f32x4 = __attribute__((ext_vector_type(4))) float;
typedef unsigned short us;
typedef unsigned long long ull;

__device__ __forceinline__ us f2h(float f) {
    union { _Float16 h; us u; } v; v.h = (_Float16)f;
    return v.u;
}
__device__ __forceinline__ void gload_lds16(const void* g, void* l) {
    __builtin_amdgcn_global_load_lds(
        (const __attribute__((address_space(1))) void*)g,
        (__attribute__((address_space(3))) void*)l, 16, 0, 0);
}

// ---- stats for BOTH tensors in one launch: per (b,c) mean & rstd (ddof=1) ----
__global__ __launch_bounds__(256) void stats2_kernel(const float* __restrict__ x0,
                                                     const float* __restrict__ x1,
                                                     float* __restrict__ mean0,
                                                     float* __restrict__ rstd0,
                                                     float* __restrict__ mean1,
                                                     float* __restrict__ rstd1) {
    int bc = blockIdx.x;
    const float* row;
    float *mean, *rstd;
    int idx;
    if (bc < Bb * Cc) { idx = bc; row = x0 + (size_t)idx * Nn; mean = mean0; rstd = rstd0; }
    else              { idx = bc - Bb * Cc; row = x1 + (size_t)idx * Nn; mean = mean1; rstd = rstd1; }
    float s = 0.f, sq = 0.f;
    for (int i = threadIdx.x * 4; i < Nn; i += 256 * 4) {
        float4 v = *reinterpret_cast<const float4*>(row + i);
        s  += v.x + v.y + v.z + v.w;
        sq += v.x*v.x + v.y*v.y + v.z*v.z + v.w*v.w;
    }
    for (int off = 32; off; off >>= 1) {
        s  += __shfl_down(s, off);
        sq += __shfl_down(sq, off);
    }
    __shared__ float ls[4], lsq[4];
    int wid = threadIdx.x >> 6;
    if ((threadIdx.x & 63) == 0) { ls[wid] = s; lsq[wid] = sq; }
    __syncthreads();
    if (threadIdx.x == 0) {
        float S  = ls[0] + ls[1] + ls[2] + ls[3];
        float SQ = lsq[0] + lsq[1] + lsq[2] + lsq[3];
        float m  = S / (float)Nn;
        float var = (SQ - S * m) / (float)(Nn - 1);
        mean[idx] = m;
        rstd[idx] = rsqrtf(var + EPS);
    }
}

// ------ pack fp32 [b][c][n] -> fp16 transposed [b][n][c], inst-norm ------
__global__ __launch_bounds__(256) void pack_T(const float* __restrict__ X,
                                              const float* __restrict__ mean,
                                              const float* __restrict__ rstd,
                                              us* __restrict__ T0) {
    int b = blockIdx.z;
    int n0 = blockIdx.x * 64, c0 = blockIdx.y * 64;
    __shared__ float tile[64][65];
    const float* Xb = X + (size_t)b * Cc * Nn;
    for (int i = threadIdx.x; i < 64 * 64; i += 256) {
        int c = i >> 6, n = i & 63;
        float v = Xb[(size_t)(c0 + c) * Nn + n0 + n];
        int cg = b * Cc + c0 + c;
        tile[c][n] = (v - mean[cg]) * rstd[cg];
    }
    __syncthreads();
    us* Pb = T0 + (size_t)b * Nn * Cc;
    for (int i = threadIdx.x; i < 64 * 64; i += 256) {
        int n = i >> 6, c = i & 63;
        Pb[(size_t)(n0 + n) * Cc + c0 + c] = f2h(tile[c][n]);
    }
}

// ------ style: ONE read -> normed SN and raw SR, both fp16 [b][n][c] ------
__global__ __launch_bounds__(256) void pack_style(const float* __restrict__ X,
                                                  const float* __restrict__ mean,
                                                  const float* __restrict__ rstd,
                                                  us* __restrict__ SNo,
                                                  us* __restrict__ SRo) {
    int b = blockIdx.z;
    int n0 = blockIdx.x * 64, c0 = blockIdx.y * 64;
    __shared__ float tile[64][65];
    const float* Xb = X + (size_t)b * Cc * Nn;
    for (int i = threadIdx.x; i < 64 * 64; i += 256) {
        int c = i >> 6, n = i & 63;
        tile[c][n] = Xb[(size_t)(c0 + c) * Nn + n0 + n];   // raw
    }
    __syncthreads();
    us* Nb = SNo + (size_t)b * Nn * Cc;
    us* Rb = SRo + (size_t)b * Nn * Cc;
    for (int i = threadIdx.x; i < 64 * 64; i += 256) {
        int n = i >> 6, c = i & 63;
        float raw = tile[c][n];
        int cg = b * Cc + c0 + c;
        size_t off = (size_t)(n0 + n) * Cc + c0 + c;
        Rb[off] = f2h(raw);
        Nb[off] = f2h((raw - mean[cg]) * rstd[cg]);
    }
}

// ------ pack the four 512x512 weights to fp16 ------
__global__ __launch_bounds__(256) void pack_w(const float* __restrict__ fw, const float* __restrict__ gw,
                                              const float* __restrict__ hw, const float* __restrict__ ow,
                                              us* __restrict__ fo, us* __restrict__ go,
                                              us* __restrict__ ho, us* __restrict__ oo) {
    int i = blockIdx.x * 256 + threadIdx.x;
    if (i >= Cc * Cc) return;
    fo[i] = f2h(fw[i]);
    go[i] = f2h(gw[i]);
    ho[i] = f2h(hw[i]);
    oo[i] = f2h(ow[i]);
}

// ------------- fp16 MFMA GEMM: C[m][n'] = sum_k A[m][k]*B[n'][k] -------------
// A m-major (lda), B n'-major (ldb). BMxBN tile, BK per barrier pair
// (BK/32 sub-tiles [rows][32]), 4 waves (2x2), frags mfma_f32_16x16x32_f16.
// LDS XOR swizzle (bank-conflict fix): element (row, slot) of a sub-tile
//   (slot = 16B column 0..3) is stored at LDS slot (slot ^ ((row>>1)&3)).
//   global_load_lds writes LDS linearly, so the SOURCE global address is
//   pre-swizzled per lane (m173 pattern); fragment reads apply the same XOR.
//   Reads then hit all 32 banks per 8-lane pass (was 4x oversubscribed).
// EPI: 0 fp32 store, 1 fp16 store.  BIAS: 0 none, 1 bias[row], 2 bias[col].
// SWZ: 0 none; 1 chunked XCD swizzle (nwg % 8 == 0);
//      2 region XCD swizzle (4x2 rectangles; gridDim.y%4==0, gridDim.x%2==0).
// blockIdx.z = batch slab via strideA/strideB/strideC.
// Epilogue: LDS-staged, vectorized float4 / packed-8B stores.
template <int EPI, int BIAS, bool RESID, int BM, int BN, int BK, int SWZ>
__global__ __launch_bounds__(256) void mfma_gemm(
    const us* __restrict__ A, int lda, long long strideA,
    const us* __restrict__ B, int ldb, long long strideB,
    void* __restrict__ out0, int ldc, long long strideC,
    const float* __restrict__ bias, const float* __restrict__ resid, long long strideR,
    int K) {
    constexpr int WM = BM / 2, WN = BN / 2;
    constexpr int MI = WM / 16, NI = WN / 16;
    constexpr int AE = BM * BK, BE = BN * BK;
    constexpr int ACH = AE / 512, BCH = BE / 512;
    __shared__ __attribute__((aligned(16))) us smem[AE + BE];
    us* As = smem;
    us* Bs = smem + AE;

    int bz = blockIdx.z;
    const us* Ab = A + (size_t)bz * strideA;
    const us* Bbp = B + (size_t)bz * strideB;

    int bx = blockIdx.x, by = blockIdx.y;
    if constexpr (SWZ == 1) {
        int nwg = gridDim.x * gridDim.y;          // must be % 8 == 0
        int bid = blockIdx.x + gridDim.x * blockIdx.y;
        int cpx = nwg >> 3;
        int swz = (bid & 7) * cpx + (bid >> 3);
        bx = swz % gridDim.x;
        by = swz / gridDim.x;
    } else if constexpr (SWZ == 2) {
        int bid = blockIdx.x + gridDim.x * blockIdx.y;
        int xcd = bid & 7;
        int idx = bid >> 3;
        int rpr = gridDim.y >> 2;
        int cpr = gridDim.x >> 1;
        int row0 = (xcd >> 1) * rpr;
        int col0 = (xcd & 1) * cpr;
        by = row0 + idx / cpr;
        bx = col0 + idx % cpr;
    }
    int m0 = by * BM, n0 = bx * BN;
    int tid = threadIdx.x, wave = tid >> 6, lane = tid & 63;
    int wr = wave >> 1, wc = wave & 1;
    int lr = lane & 15, lg = lane >> 4;

    f32x4 acc[MI][NI];
#pragma unroll
    for (int i = 0; i < MI; ++i)
#pragma unroll
        for (int j = 0; j < NI; ++j) acc[i][j] = (f32x4){0.f, 0.f, 0.f, 0.f};

    for (int k0 = 0; k0 < K; k0 += BK) {
        __syncthreads();
        // stage with pre-swizzled global source (LDS dest linear per lane)
#pragma unroll
        for (int ch = wave; ch < ACH; ch += 4) {
            int e0 = ch * 512 + lane * 8;
            int kb = e0 / (BM * 32);
            int rem = e0 - kb * (BM * 32);
            int rr = rem >> 5;
            int gslot = ((rem & 31) >> 3) ^ ((rr >> 1) & 3);   // XOR involution
            gload_lds16(Ab + (size_t)(m0 + rr) * lda + k0 + kb * 32 + gslot * 8,
                        As + ch * 512);
        }
#pragma unroll
        for (int ch = wave; ch < BCH; ch += 4) {
            int e0 = ch * 512 + lane * 8;
            int kb = e0 / (BN * 32);
            int rem = e0 - kb * (BN * 32);
            int rr = rem >> 5;
            int gslot = ((rem & 31) >> 3) ^ ((rr >> 1) & 3);
            gload_lds16(Bbp + (size_t)(n0 + rr) * ldb + k0 + kb * 32 + gslot * 8,
                        Bs + ch * 512);
        }
        asm volatile("s_waitcnt vmcnt(0)" ::: "memory");
        __syncthreads();

#pragma unroll
        for (int kb = 0; kb < BK / 32; ++kb) {
            const us* Abase = As + kb * BM * 32;
            const us* Bbase = Bs + kb * BN * 32;
            f16x8 a[MI], b[NI];
#pragma unroll
            for (int x = 0; x < MI; ++x) {
                int row = wr * WM + x * 16 + lr;
                a[x] = *reinterpret_cast<const f16x8*>(
                    &Abase[row * 32 + ((lg ^ ((row >> 1) & 3)) << 3)]);
            }
#pragma unroll
            for (int x = 0; x < NI; ++x) {
                int row = wc * WN + x * 16 + lr;
                b[x] = *reinterpret_cast<const f16x8*>(
                    &Bbase[row * 32 + ((lg ^ ((row >> 1) & 3)) << 3)]);
            }
#pragma unroll
            for (int mi = 0; mi < MI; ++mi)
#pragma unroll
                for (int ni = 0; ni < NI; ++ni)
                    acc[mi][ni] = __builtin_amdgcn_mfma_f32_16x16x32_f16(a[mi], b[ni], acc[mi][ni], 0, 0, 0);
        }
    }

    // -------- LDS-staged epilogue: per mi, stage 32 rows x BN, store wide --------
    constexpr int SP = BN + 4;                 // padded f32 stride
    float* sst = reinterpret_cast<float*>(smem);
    constexpr int CSEG = BN / 8;               // cols per thread (8 thr/row, 32 rows)
    int rl = tid >> 3;                         // 0..31 staged-row
    int cb = (tid & 7) * CSEG;                 // col base for readback
#pragma unroll
    for (int mi = 0; mi < MI; ++mi) {
        __syncthreads();
#pragma unroll
        for (int ni = 0; ni < NI; ++ni) {
#pragma unroll
            for (int r = 0; r < 4; ++r)
                sst[(wr * 16 + lg * 4 + r) * SP + wc * WN + ni * 16 + lr] = acc[mi][ni][r];
        }
        __syncthreads();
        int grow = m0 + (rl >> 4) * WM + mi * 16 + (rl & 15);
        float bs = 0.f;
        if constexpr (BIAS == 1) bs = bias[grow];
#pragma unroll
        for (int j = 0; j < CSEG / 4; ++j) {
            int col = n0 + cb + j * 4;
            float4 v = *reinterpret_cast<const float4*>(&sst[rl * SP + cb + j * 4]);
            if constexpr (BIAS == 1) { v.x += bs; v.y += bs; v.z += bs; v.w += bs; }
            if constexpr (BIAS == 2) {
                const float4 bv = *reinterpret_cast<const float4*>(&bias[col]);
                v.x += bv.x; v.y += bv.y; v.z += bv.z; v.w += bv.w;
            }
            size_t off = (size_t)bz * strideC + (size_t)grow * ldc + col;
            if constexpr (RESID) {
                const float4 rr4 = *reinterpret_cast<const float4*>(
                    &resid[(size_t)bz * strideR + (size_t)grow * ldc + col]);
                v.x += rr4.x; v.y += rr4.y; v.z += rr4.z; v.w += rr4.w;
            }
            if constexpr (EPI == 0) {
                *reinterpret_cast<float4*>(&((float*)out0)[off]) = v;
            } else {
                ull pk = (ull)f2h(v.x) | ((ull)f2h(v.y) << 16)
                       | ((ull)f2h(v.z) << 32) | ((ull)f2h(v.w) << 48);
                *reinterpret_cast<ull*>(&((us*)out0)[off]) = pk;
            }
        }
    }
}

// ------- row softmax fp16 IN-PLACE (S row -> normalized P row) -------
// grid (Nn, nslab): blockIdx.y selects a 32MB S slab.
__global__ __launch_bounds__(256) void softmax_kernel(us* __restrict__ S) {
    us* rowp = S + (size_t)blockIdx.y * ((size_t)Nn * Nn) + (size_t)blockIdx.x * Nn;
    f16x8* r8 = reinterpret_cast<f16x8*>(rowp);
    int t = threadIdx.x;
    float f[16];
    float mx = -1e30f;
#pragma unroll
    for (int j = 0; j < 2; ++j) {
        f16x8 v = r8[t + 256 * j];
#pragma unroll
        for (int e = 0; e < 8; ++e) {
            f[j * 8 + e] = (float)v[e];
            mx = fmaxf(mx, f[j * 8 + e]);
        }
    }
    for (int off = 32; off; off >>= 1) mx = fmaxf(mx, __shfl_down(mx, off));
    __shared__ float redm[4], reds[4];
    int wid = t >> 6;
    if ((t & 63) == 0) redm[wid] = mx;
    __syncthreads();
    mx = fmaxf(fmaxf(redm[0], redm[1]), fmaxf(redm[2], redm[3]));
    float s = 0.f;
#pragma unroll
    for (int j = 0; j < 16; ++j) {
        f[j] = __expf(f[j] - mx);
        s += f[j];
    }
    for (int off = 32; off; off >>= 1) s += __shfl_down(s, off);
    if ((t & 63) == 0) reds[wid] = s;
    __syncthreads();
    s = reds[0] + reds[1] + reds[2] + reds[3];
    float inv = 1.f / s;
#pragma unroll
    for (int j = 0; j < 2; ++j) {
        f16x8 o;
#pragma unroll
        for (int e = 0; e < 8; ++e) o[e] = (_Float16)(f[j * 8 + e] * inv);
        r8[t + 256 * j] = o;
    }
}

extern "C" void kernel_launch(void* const* d_in, const int* in_sizes, int n_in,
                              void* d_out, int out_size, void* d_ws, size_t ws_size,
                              hipStream_t stream) {
    const float* content = (const float*)d_in[0];
    const float* style   = (const float*)d_in[1];
    const float* f_w = (const float*)d_in[2];
    const float* f_b = (const float*)d_in[3];
    const float* g_w = (const float*)d_in[4];
    const float* g_b = (const float*)d_in[5];
    const float* h_w = (const float*)d_in[6];
    const float* h_b = (const float*)d_in[7];
    const float* o_w = (const float*)d_in[8];
    const float* o_b = (const float*)d_in[9];
    float* out = (float*)d_out;
    char* ws = (char*)d_ws;

    const size_t PB   = (size_t)Cc * Nn;       // 2,097,152 elems per batch-plane
    const size_t TEN  = PB * Bb;               // 8,388,608 elems (16 MB as fp16)
    const size_t SMAT = (size_t)Nn * Nn;       // 16,777,216 elems (32 MB as fp16)

    // Workspace layout (peak ~194 MB, proven <= r5's 214 MB):
    // [0,64MB): conv outputs fp16 (FT, GT, Hbf, OT)
    us* FT  = (us*)ws;                         // F^T [q][c]
    us* GT  = FT + TEN;                        // G^T [s][c]
    us* Hbf = GT + TEN;                        // H   [c'][s]
    us* OT  = Hbf + TEN;                       // O^T [q][c']
    // [64,66MB): weights fp16 + stats
    us* fwh = OT + TEN;
    us* gwh = fwh + Cc * Cc;
    us* hwb = gwh + Cc * Cc;
    us* owb = hwb + Cc * Cc;
    float* meanC = (float*)(owb + Cc * Cc);
    float* rstdC = meanC + Bb * Cc;
    float* meanS = rstdC + Bb * Cc;
    float* rstdS = meanS + Bb * Cc;
    // [66,114MB): packed inputs fp16 (CN, SN, SR) — dead before attention.
    us* CN = (us*)(rstdS + Bb * Cc);
    us* SN = CN + TEN;
    us* SR = SN + TEN;
    // [66,194MB): S/P fp16, ALL FOUR batches — overlays dead CN/SN/SR.
    us* S4 = CN;

    stats2_kernel<<<2 * Bb * Cc, 256, 0, stream>>>(content, style,
                                                   meanC, rstdC, meanS, rstdS);

    dim3 pgrid(Nn / 64, Cc / 64, Bb);
    pack_T<<<pgrid, 256, 0, stream>>>(content, meanC, rstdC, CN);
    pack_style<<<pgrid, 256, 0, stream>>>(style, meanS, rstdS, SN, SR);
    pack_w<<<(Cc * Cc + 255) / 256, 256, 0, stream>>>(f_w, g_w, h_w, o_w,
                                                      fwh, gwh, hwb, owb);

    // F^T[q][c'] = sum_c CN[q][c] f_w[c'][c] + f_b[c']  (M=4096,N=512,K=512)
    mfma_gemm<1, 2, false, 64, 64, 64, 1><<<dim3(Cc / 64, Nn / 64, Bb), 256, 0, stream>>>(
        CN, Cc, (long long)PB, fwh, Cc, 0,
        FT, Cc, (long long)PB, f_b, nullptr, 0, Cc);
    // G^T likewise
    mfma_gemm<1, 2, false, 64, 64, 64, 1><<<dim3(Cc / 64, Nn / 64, Bb), 256, 0, stream>>>(
        SN, Cc, (long long)PB, gwh, Cc, 0,
        GT, Cc, (long long)PB, g_b, nullptr, 0, Cc);
    // H[c'][s] = sum_c h_w[c'][c] SR[s][c] + h_b[c']   (M=512,N=4096,K=512)
    mfma_gemm<1, 1, false, 64, 64, 64, 1><<<dim3(Nn / 64, Cc / 64, Bb), 256, 0, stream>>>(
        hwb, Cc, 0, SR, Cc, (long long)PB,
        Hbf, Nn, (long long)PB, h_b, nullptr, 0, Cc);
    // (CN/SN/SR are now dead; S4 overlays them.)

    // S[q][s] = sum_c F^T[q][c] G^T[s][c]  (M=N=4096,K=512), fp16 out, all batches
    mfma_gemm<1, 0, false, 128, 128, 64, 2><<<dim3(32, 32, Bb), 256, 0, stream>>>(
        FT, Cc, (long long)PB, GT, Cc, (long long)PB,
        S4, Nn, (long long)SMAT, nullptr, nullptr, 0, Cc);
    softmax_kernel<<<dim3(Nn, Bb), 256, 0, stream>>>(S4);
    // O^T[q][c'] = sum_s P[q][s] H[c'][s]  (M=4096,N=512,K=4096), fp16 out
    mfma_gemm<1, 0, false, 64, 64, 64, 1><<<dim3(Cc / 64, Nn / 64, Bb), 256, 0, stream>>>(
        S4, Nn, (long long)SMAT, Hbf, Nn, (long long)PB,
        OT, Cc, (long long)PB, nullptr, nullptr, 0, Nn);

    // out[c'][n] = sum_c o_w[c'][c] O^T[n][c] + o_b[c'] + content[c'][n]
    mfma_gemm<0, 1, true, 64, 64, 64, 1><<<dim3(Nn / 64, Cc / 64, Bb), 256, 0, stream>>>(
        owb, Cc, 0, OT, Cc, (long long)PB,
        out, Nn, (long long)PB, o_b, content, (long long)PB, Cc);
}

// Round 17
// 325.610 us; speedup vs baseline: 1.1626x; 1.1020x over previous
//
#include <hip/hip_runtime.h>

constexpr int Cc = 512;
constexpr int Nn = 4096;   // 64*64
constexpr int Bb = 4;
#define EPS 1e-5f

using f16x8 = __attribute__((ext_vector_type(8))) _Float16;
using f32x4 = __attribute__((ext_vector_type(4))) float;
typedef unsigned short us;
typedef unsigned long long ull;

__device__ __forceinline__ us f2h(float f) {
    union { _Float16 h; us u; } v; v.h = (_Float16)f;
    return v.u;
}
__device__ __forceinline__ void gload_lds16(const void* g, void* l) {
    __builtin_amdgcn_global_load_lds(
        (const __attribute__((address_space(1))) void*)g,
        (__attribute__((address_space(3))) void*)l, 16, 0, 0);
}

// ---- stats for BOTH tensors in one launch: per (b,c) mean & rstd (ddof=1) ----
__global__ __launch_bounds__(256) void stats2_kernel(const float* __restrict__ x0,
                                                     const float* __restrict__ x1,
                                                     float* __restrict__ mean0,
                                                     float* __restrict__ rstd0,
                                                     float* __restrict__ mean1,
                                                     float* __restrict__ rstd1) {
    int bc = blockIdx.x;
    const float* row;
    float *mean, *rstd;
    int idx;
    if (bc < Bb * Cc) { idx = bc; row = x0 + (size_t)idx * Nn; mean = mean0; rstd = rstd0; }
    else              { idx = bc - Bb * Cc; row = x1 + (size_t)idx * Nn; mean = mean1; rstd = rstd1; }
    float s = 0.f, sq = 0.f;
    for (int i = threadIdx.x * 4; i < Nn; i += 256 * 4) {
        float4 v = *reinterpret_cast<const float4*>(row + i);
        s  += v.x + v.y + v.z + v.w;
        sq += v.x*v.x + v.y*v.y + v.z*v.z + v.w*v.w;
    }
    for (int off = 32; off; off >>= 1) {
        s  += __shfl_down(s, off);
        sq += __shfl_down(sq, off);
    }
    __shared__ float ls[4], lsq[4];
    int wid = threadIdx.x >> 6;
    if ((threadIdx.x & 63) == 0) { ls[wid] = s; lsq[wid] = sq; }
    __syncthreads();
    if (threadIdx.x == 0) {
        float S  = ls[0] + ls[1] + ls[2] + ls[3];
        float SQ = lsq[0] + lsq[1] + lsq[2] + lsq[3];
        float m  = S / (float)Nn;
        float var = (SQ - S * m) / (float)(Nn - 1);
        mean[idx] = m;
        rstd[idx] = rsqrtf(var + EPS);
    }
}

// ------ pack fp32 [b][c][n] -> fp16 transposed [b][n][c], inst-norm ------
__global__ __launch_bounds__(256) void pack_T(const float* __restrict__ X,
                                              const float* __restrict__ mean,
                                              const float* __restrict__ rstd,
                                              us* __restrict__ T0) {
    int b = blockIdx.z;
    int n0 = blockIdx.x * 64, c0 = blockIdx.y * 64;
    __shared__ float tile[64][65];
    const float* Xb = X + (size_t)b * Cc * Nn;
    for (int i = threadIdx.x; i < 64 * 64; i += 256) {
        int c = i >> 6, n = i & 63;
        float v = Xb[(size_t)(c0 + c) * Nn + n0 + n];
        int cg = b * Cc + c0 + c;
        tile[c][n] = (v - mean[cg]) * rstd[cg];
    }
    __syncthreads();
    us* Pb = T0 + (size_t)b * Nn * Cc;
    for (int i = threadIdx.x; i < 64 * 64; i += 256) {
        int n = i >> 6, c = i & 63;
        Pb[(size_t)(n0 + n) * Cc + c0 + c] = f2h(tile[c][n]);
    }
}

// ------ style: ONE read -> normed SN and raw SR, both fp16 [b][n][c] ------
__global__ __launch_bounds__(256) void pack_style(const float* __restrict__ X,
                                                  const float* __restrict__ mean,
                                                  const float* __restrict__ rstd,
                                                  us* __restrict__ SNo,
                                                  us* __restrict__ SRo) {
    int b = blockIdx.z;
    int n0 = blockIdx.x * 64, c0 = blockIdx.y * 64;
    __shared__ float tile[64][65];
    const float* Xb = X + (size_t)b * Cc * Nn;
    for (int i = threadIdx.x; i < 64 * 64; i += 256) {
        int c = i >> 6, n = i & 63;
        tile[c][n] = Xb[(size_t)(c0 + c) * Nn + n0 + n];   // raw
    }
    __syncthreads();
    us* Nb = SNo + (size_t)b * Nn * Cc;
    us* Rb = SRo + (size_t)b * Nn * Cc;
    for (int i = threadIdx.x; i < 64 * 64; i += 256) {
        int n = i >> 6, c = i & 63;
        float raw = tile[c][n];
        int cg = b * Cc + c0 + c;
        size_t off = (size_t)(n0 + n) * Cc + c0 + c;
        Rb[off] = f2h(raw);
        Nb[off] = f2h((raw - mean[cg]) * rstd[cg]);
    }
}

// ------ pack the four 512x512 weights to fp16 ------
__global__ __launch_bounds__(256) void pack_w(const float* __restrict__ fw, const float* __restrict__ gw,
                                              const float* __restrict__ hw, const float* __restrict__ ow,
                                              us* __restrict__ fo, us* __restrict__ go,
                                              us* __restrict__ ho, us* __restrict__ oo) {
    int i = blockIdx.x * 256 + threadIdx.x;
    if (i >= Cc * Cc) return;
    fo[i] = f2h(fw[i]);
    go[i] = f2h(gw[i]);
    ho[i] = f2h(hw[i]);
    oo[i] = f2h(ow[i]);
}

// ------------- fp16 MFMA GEMM: C[m][n'] = sum_k A[m][k]*B[n'][k] -------------
// A m-major (lda), B n'-major (ldb). BMxBN tile, BK per step, 4 waves (2x2),
// frags mfma_f32_16x16x32_f16. DOUBLE-BUFFERED LDS (T3 2-phase): stage tile
// t+1 into buf^1 BEFORE computing buf, one vmcnt(0)+barrier per step -> HBM/L2
// latency hides under compute.
// LDS XOR swizzle (bank-conflict fix): slot ^= (row>>1)&3, applied via
// pre-swizzled global source (LDS dest linear) and on fragment reads.
// EPI: 0 fp32 store, 1 fp16 store.  BIAS: 0 none, 1 bias[row], 2 bias[col].
// SWZ: 0 none; 1 chunked XCD swizzle (nwg % 8 == 0);
//      2 region XCD swizzle (4x2 rectangles; gridDim.y%4==0, gridDim.x%2==0).
// blockIdx.z = batch slab via strideA/strideB/strideC.
// Epilogue: LDS-staged, vectorized float4 / packed-8B stores.
template <int EPI, int BIAS, bool RESID, int BM, int BN, int BK, int SWZ>
__global__ __launch_bounds__(256) void mfma_gemm(
    const us* __restrict__ A, int lda, long long strideA,
    const us* __restrict__ B, int ldb, long long strideB,
    void* __restrict__ out0, int ldc, long long strideC,
    const float* __restrict__ bias, const float* __restrict__ resid, long long strideR,
    int K) {
    constexpr int WM = BM / 2, WN = BN / 2;
    constexpr int MI = WM / 16, NI = WN / 16;
    constexpr int AE = BM * BK, BE = BN * BK;
    constexpr int BUFSZ = AE + BE;
    constexpr int ACH = AE / 512, BCH = BE / 512;
    __shared__ __attribute__((aligned(16))) us smem[2 * BUFSZ];

    int bz = blockIdx.z;
    const us* Ab = A + (size_t)bz * strideA;
    const us* Bbp = B + (size_t)bz * strideB;

    int bx = blockIdx.x, by = blockIdx.y;
    if constexpr (SWZ == 1) {
        int nwg = gridDim.x * gridDim.y;          // must be % 8 == 0
        int bid = blockIdx.x + gridDim.x * blockIdx.y;
        int cpx = nwg >> 3;
        int swz = (bid & 7) * cpx + (bid >> 3);
        bx = swz % gridDim.x;
        by = swz / gridDim.x;
    } else if constexpr (SWZ == 2) {
        int bid = blockIdx.x + gridDim.x * blockIdx.y;
        int xcd = bid & 7;
        int idx = bid >> 3;
        int rpr = gridDim.y >> 2;
        int cpr = gridDim.x >> 1;
        int row0 = (xcd >> 1) * rpr;
        int col0 = (xcd & 1) * cpr;
        by = row0 + idx / cpr;
        bx = col0 + idx % cpr;
    }
    int m0 = by * BM, n0 = bx * BN;
    int tid = threadIdx.x, wave = tid >> 6, lane = tid & 63;
    int wr = wave >> 1, wc = wave & 1;
    int lr = lane & 15, lg = lane >> 4;

    // stage tile at K-offset k0 into buffer buf (pre-swizzled global source)
    auto stage = [&](int buf, int k0) {
        us* Asb = smem + buf * BUFSZ;
        us* Bsb = Asb + AE;
#pragma unroll
        for (int ch = wave; ch < ACH; ch += 4) {
            int e0 = ch * 512 + lane * 8;
            int kb = e0 / (BM * 32);
            int rem = e0 - kb * (BM * 32);
            int rr = rem >> 5;
            int gslot = ((rem & 31) >> 3) ^ ((rr >> 1) & 3);
            gload_lds16(Ab + (size_t)(m0 + rr) * lda + k0 + kb * 32 + gslot * 8,
                        Asb + ch * 512);
        }
#pragma unroll
        for (int ch = wave; ch < BCH; ch += 4) {
            int e0 = ch * 512 + lane * 8;
            int kb = e0 / (BN * 32);
            int rem = e0 - kb * (BN * 32);
            int rr = rem >> 5;
            int gslot = ((rem & 31) >> 3) ^ ((rr >> 1) & 3);
            gload_lds16(Bbp + (size_t)(n0 + rr) * ldb + k0 + kb * 32 + gslot * 8,
                        Bsb + ch * 512);
        }
    };

    f32x4 acc[MI][NI];
#pragma unroll
    for (int i = 0; i < MI; ++i)
#pragma unroll
        for (int j = 0; j < NI; ++j) acc[i][j] = (f32x4){0.f, 0.f, 0.f, 0.f};

    stage(0, 0);
    asm volatile("s_waitcnt vmcnt(0)" ::: "memory");
    __syncthreads();

    int nsteps = K / BK;
    for (int t = 0; t < nsteps; ++t) {
        int cur = t & 1;
        if (t + 1 < nsteps) stage(cur ^ 1, (t + 1) * BK);   // prefetch in flight
        const us* As = smem + cur * BUFSZ;
        const us* Bs = As + AE;
#pragma unroll
        for (int kb = 0; kb < BK / 32; ++kb) {
            const us* Abase = As + kb * BM * 32;
            const us* Bbase = Bs + kb * BN * 32;
            f16x8 a[MI], b[NI];
#pragma unroll
            for (int x = 0; x < MI; ++x) {
                int row = wr * WM + x * 16 + lr;
                a[x] = *reinterpret_cast<const f16x8*>(
                    &Abase[row * 32 + ((lg ^ ((row >> 1) & 3)) << 3)]);
            }
#pragma unroll
            for (int x = 0; x < NI; ++x) {
                int row = wc * WN + x * 16 + lr;
                b[x] = *reinterpret_cast<const f16x8*>(
                    &Bbase[row * 32 + ((lg ^ ((row >> 1) & 3)) << 3)]);
            }
#pragma unroll
            for (int mi = 0; mi < MI; ++mi)
#pragma unroll
                for (int ni = 0; ni < NI; ++ni)
                    acc[mi][ni] = __builtin_amdgcn_mfma_f32_16x16x32_f16(a[mi], b[ni], acc[mi][ni], 0, 0, 0);
        }
        asm volatile("s_waitcnt vmcnt(0)" ::: "memory");  // prefetch landed
        __syncthreads();                                   // all reads of cur done
    }

    // -------- LDS-staged epilogue: per mi, stage 32 rows x BN, store wide --------
    constexpr int SP = BN + 4;                 // padded f32 stride
    float* sst = reinterpret_cast<float*>(smem);
    constexpr int CSEG = BN / 8;               // cols per thread (8 thr/row, 32 rows)
    int rl = tid >> 3;                         // 0..31 staged-row
    int cb = (tid & 7) * CSEG;                 // col base for readback
#pragma unroll
    for (int mi = 0; mi < MI; ++mi) {
        __syncthreads();
#pragma unroll
        for (int ni = 0; ni < NI; ++ni) {
#pragma unroll
            for (int r = 0; r < 4; ++r)
                sst[(wr * 16 + lg * 4 + r) * SP + wc * WN + ni * 16 + lr] = acc[mi][ni][r];
        }
        __syncthreads();
        int grow = m0 + (rl >> 4) * WM + mi * 16 + (rl & 15);
        float bs = 0.f;
        if constexpr (BIAS == 1) bs = bias[grow];
#pragma unroll
        for (int j = 0; j < CSEG / 4; ++j) {
            int col = n0 + cb + j * 4;
            float4 v = *reinterpret_cast<const float4*>(&sst[rl * SP + cb + j * 4]);
            if constexpr (BIAS == 1) { v.x += bs; v.y += bs; v.z += bs; v.w += bs; }
            if constexpr (BIAS == 2) {
                const float4 bv = *reinterpret_cast<const float4*>(&bias[col]);
                v.x += bv.x; v.y += bv.y; v.z += bv.z; v.w += bv.w;
            }
            size_t off = (size_t)bz * strideC + (size_t)grow * ldc + col;
            if constexpr (RESID) {
                const float4 rr4 = *reinterpret_cast<const float4*>(
                    &resid[(size_t)bz * strideR + (size_t)grow * ldc + col]);
                v.x += rr4.x; v.y += rr4.y; v.z += rr4.z; v.w += rr4.w;
            }
            if constexpr (EPI == 0) {
                *reinterpret_cast<float4*>(&((float*)out0)[off]) = v;
            } else {
                ull pk = (ull)f2h(v.x) | ((ull)f2h(v.y) << 16)
                       | ((ull)f2h(v.z) << 32) | ((ull)f2h(v.w) << 48);
                *reinterpret_cast<ull*>(&((us*)out0)[off]) = pk;
            }
        }
    }
}

// ------- row softmax fp16 IN-PLACE (S row -> normalized P row) -------
// grid (Nn, nslab): blockIdx.y selects a 32MB S slab.
__global__ __launch_bounds__(256) void softmax_kernel(us* __restrict__ S) {
    us* rowp = S + (size_t)blockIdx.y * ((size_t)Nn * Nn) + (size_t)blockIdx.x * Nn;
    f16x8* r8 = reinterpret_cast<f16x8*>(rowp);
    int t = threadIdx.x;
    float f[16];
    float mx = -1e30f;
#pragma unroll
    for (int j = 0; j < 2; ++j) {
        f16x8 v = r8[t + 256 * j];
#pragma unroll
        for (int e = 0; e < 8; ++e) {
            f[j * 8 + e] = (float)v[e];
            mx = fmaxf(mx, f[j * 8 + e]);
        }
    }
    for (int off = 32; off; off >>= 1) mx = fmaxf(mx, __shfl_down(mx, off));
    __shared__ float redm[4], reds[4];
    int wid = t >> 6;
    if ((t & 63) == 0) redm[wid] = mx;
    __syncthreads();
    mx = fmaxf(fmaxf(redm[0], redm[1]), fmaxf(redm[2], redm[3]));
    float s = 0.f;
#pragma unroll
    for (int j = 0; j < 16; ++j) {
        f[j] = __expf(f[j] - mx);
        s += f[j];
    }
    for (int off = 32; off; off >>= 1) s += __shfl_down(s, off);
    if ((t & 63) == 0) reds[wid] = s;
    __syncthreads();
    s = reds[0] + reds[1] + reds[2] + reds[3];
    float inv = 1.f / s;
#pragma unroll
    for (int j = 0; j < 2; ++j) {
        f16x8 o;
#pragma unroll
        for (int e = 0; e < 8; ++e) o[e] = (_Float16)(f[j * 8 + e] * inv);
        r8[t + 256 * j] = o;
    }
}

extern "C" void kernel_launch(void* const* d_in, const int* in_sizes, int n_in,
                              void* d_out, int out_size, void* d_ws, size_t ws_size,
                              hipStream_t stream) {
    const float* content = (const float*)d_in[0];
    const float* style   = (const float*)d_in[1];
    const float* f_w = (const float*)d_in[2];
    const float* f_b = (const float*)d_in[3];
    const float* g_w = (const float*)d_in[4];
    const float* g_b = (const float*)d_in[5];
    const float* h_w = (const float*)d_in[6];
    const float* h_b = (const float*)d_in[7];
    const float* o_w = (const float*)d_in[8];
    const float* o_b = (const float*)d_in[9];
    float* out = (float*)d_out;
    char* ws = (char*)d_ws;

    const size_t PB   = (size_t)Cc * Nn;       // 2,097,152 elems per batch-plane
    const size_t TEN  = PB * Bb;               // 8,388,608 elems (16 MB as fp16)
    const size_t SMAT = (size_t)Nn * Nn;       // 16,777,216 elems (32 MB as fp16)

    // Workspace layout (peak ~194 MB, proven <= r5's 214 MB):
    // [0,64MB): conv outputs fp16 (FT, GT, Hbf, OT)
    us* FT  = (us*)ws;                         // F^T [q][c]
    us* GT  = FT + TEN;                        // G^T [s][c]
    us* Hbf = GT + TEN;                        // H   [c'][s]
    us* OT  = Hbf + TEN;                       // O^T [q][c']
    // [64,66MB): weights fp16 + stats
    us* fwh = OT + TEN;
    us* gwh = fwh + Cc * Cc;
    us* hwb = gwh + Cc * Cc;
    us* owb = hwb + Cc * Cc;
    float* meanC = (float*)(owb + Cc * Cc);
    float* rstdC = meanC + Bb * Cc;
    float* meanS = rstdC + Bb * Cc;
    float* rstdS = meanS + Bb * Cc;
    // [66,114MB): packed inputs fp16 (CN, SN, SR) — dead before attention.
    us* CN = (us*)(rstdS + Bb * Cc);
    us* SN = CN + TEN;
    us* SR = SN + TEN;
    // [66,194MB): S/P fp16, ALL FOUR batches — overlays dead CN/SN/SR.
    us* S4 = CN;

    stats2_kernel<<<2 * Bb * Cc, 256, 0, stream>>>(content, style,
                                                   meanC, rstdC, meanS, rstdS);

    dim3 pgrid(Nn / 64, Cc / 64, Bb);
    pack_T<<<pgrid, 256, 0, stream>>>(content, meanC, rstdC, CN);
    pack_style<<<pgrid, 256, 0, stream>>>(style, meanS, rstdS, SN, SR);
    pack_w<<<(Cc * Cc + 255) / 256, 256, 0, stream>>>(f_w, g_w, h_w, o_w,
                                                      fwh, gwh, hwb, owb);

    // F^T[q][c'] = sum_c CN[q][c] f_w[c'][c] + f_b[c']  (M=4096,N=512,K=512)
    mfma_gemm<1, 2, false, 64, 64, 64, 1><<<dim3(Cc / 64, Nn / 64, Bb), 256, 0, stream>>>(
        CN, Cc, (long long)PB, fwh, Cc, 0,
        FT, Cc, (long long)PB, f_b, nullptr, 0, Cc);
    // G^T likewise
    mfma_gemm<1, 2, false, 64, 64, 64, 1><<<dim3(Cc / 64, Nn / 64, Bb), 256, 0, stream>>>(
        SN, Cc, (long long)PB, gwh, Cc, 0,
        GT, Cc, (long long)PB, g_b, nullptr, 0, Cc);
    // H[c'][s] = sum_c h_w[c'][c] SR[s][c] + h_b[c']   (M=512,N=4096,K=512)
    mfma_gemm<1, 1, false, 64, 64, 64, 1><<<dim3(Nn / 64, Cc / 64, Bb), 256, 0, stream>>>(
        hwb, Cc, 0, SR, Cc, (long long)PB,
        Hbf, Nn, (long long)PB, h_b, nullptr, 0, Cc);
    // (CN/SN/SR are now dead; S4 overlays them.)

    // S[q][s] = sum_c F^T[q][c] G^T[s][c]  (M=N=4096,K=512), fp16 out, all batches
    mfma_gemm<1, 0, false, 128, 128, 64, 2><<<dim3(32, 32, Bb), 256, 0, stream>>>(
        FT, Cc, (long long)PB, GT, Cc, (long long)PB,
        S4, Nn, (long long)SMAT, nullptr, nullptr, 0, Cc);
    softmax_kernel<<<dim3(Nn, Bb), 256, 0, stream>>>(S4);
    // O^T[q][c'] = sum_s P[q][s] H[c'][s]  (M=4096,N=512,K=4096), fp16 out
    // 128x128 tile (half the per-output LDS traffic) + dbuf pipeline
    mfma_gemm<1, 0, false, 128, 128, 64, 1><<<dim3(Cc / 128, Nn / 128, Bb), 256, 0, stream>>>(
        S4, Nn, (long long)SMAT, Hbf, Nn, (long long)PB,
        OT, Cc, (long long)PB, nullptr, nullptr, 0, Nn);

    // out[c'][n] = sum_c o_w[c'][c] O^T[n][c] + o_b[c'] + content[c'][n]
    mfma_gemm<0, 1, true, 64, 64, 64, 1><<<dim3(Nn / 64, Cc / 64, Bb), 256, 0, stream>>>(
        owb, Cc, 0, OT, Cc, (long long)PB,
        out, Nn, (long long)PB, o_b, content, (long long)PB, Cc);
}